// Round 1
// baseline (6426.196 us; speedup 1.0000x reference)
//
#include <hip/hip_runtime.h>
#include <cstdint>

#define TT 512
#define BB 128
#define DD 512
#define HH 512
#define KTOT 1024
#define LDK 1032   // padded K stride in LDS (bf16 elements)

typedef short bf16x8 __attribute__((ext_vector_type(8)));
typedef float f32x4 __attribute__((ext_vector_type(4)));

__device__ inline unsigned short f2bfs(float f) {
    unsigned int u = __builtin_bit_cast(unsigned int, f);
    u = (u + 0x7FFFu + ((u >> 16) & 1u)) >> 16;
    return (unsigned short)u;
}

__device__ inline bf16x8 load8w(const float* p) {
    const float4* p4 = (const float4*)p;
    float4 a = p4[0];
    float4 b = p4[1];
    bf16x8 r;
    r[0] = (short)f2bfs(a.x); r[1] = (short)f2bfs(a.y);
    r[2] = (short)f2bfs(a.z); r[3] = (short)f2bfs(a.w);
    r[4] = (short)f2bfs(b.x); r[5] = (short)f2bfs(b.y);
    r[6] = (short)f2bfs(b.z); r[7] = (short)f2bfs(b.w);
    return r;
}

__global__ __launch_bounds__(256, 1) void qlstm_kernel(
    const float* __restrict__ X,
    const float* __restrict__ Wf, const float* __restrict__ bfb,
    const float* __restrict__ Wi, const float* __restrict__ bi,
    const float* __restrict__ Wu, const float* __restrict__ bu,
    const float* __restrict__ Wo, const float* __restrict__ bo,
    const float* __restrict__ Ws1, const float* __restrict__ bs1,
    const float* __restrict__ Ws2, const float* __restrict__ bs2,
    float* __restrict__ out,
    unsigned int* __restrict__ cnt,      // [8][TT] step barrier counters
    unsigned short* __restrict__ hbuf)   // [2][BB][HH] bf16 ping-pong
{
    const int tid  = threadIdx.x;
    const int bid  = blockIdx.x;
    const int rg   = bid >> 5;    // rowgroup 0..7  (16 batch rows)
    const int cg   = bid & 31;    // colgroup 0..31 (16 h cols)
    const int b0   = rg * 16;
    const int lane = tid & 63;
    const int wv   = tid >> 6;    // wave 0..3 -> K chunk of 256
    const int qd   = lane >> 4;
    const int nn   = lane & 15;

    __shared__ unsigned short comb[16][LDK];   // staged [x|h] rows, bf16
    __shared__ float pc[4][4][16][16];         // [gate][wave][m][n] partials
    __shared__ float fld[16];                  // f gate per local row

    // ---- one-time: weight B-fragments into registers ----
    bf16x8 wfi[8], wfu[8], wfo[8], wff[8];
    {
        const size_t hcol = (size_t)(cg * 16 + nn);
        bf16x8 z8; 
        #pragma unroll
        for (int j = 0; j < 8; ++j) z8[j] = 0;
        #pragma unroll
        for (int kk = 0; kk < 8; ++kk) {
            const int k = wv * 256 + kk * 32 + qd * 8;
            wfi[kk] = load8w(Wi + hcol * KTOT + k);
            wfu[kk] = load8w(Wu + hcol * KTOT + k);
            wfo[kk] = load8w(Wo + hcol * KTOT + k);
            wff[kk] = (nn < 2) ? load8w(Wf + (size_t)nn * KTOT + k) : z8;
        }
    }

    // ---- one-time: small params into registers ----
    const int fm = tid >> 4, fn = tid & 15;        // final-phase element
    const int gcol = cg * 16 + fn;
    const float bir = bi[gcol], bur = bu[gcol], bor = bo[gcol];
    float bfr0 = 0.f, bfr1 = 0.f, ws1r[8], bs1r[4], ws2r[8], bs2r0 = 0.f, bs2r1 = 0.f;
    if (tid < 16) {
        bfr0 = bfb[0]; bfr1 = bfb[1];
        #pragma unroll
        for (int j = 0; j < 8; ++j) ws1r[j] = Ws1[j];
        #pragma unroll
        for (int j = 0; j < 4; ++j) bs1r[j] = bs1[j];
        #pragma unroll
        for (int j = 0; j < 8; ++j) ws2r[j] = Ws2[j];
        bs2r0 = bs2[0]; bs2r1 = bs2[1];
    }

    float cval = 0.f;   // persistent cell state for (fm, fn)

    for (int t = 0; t < TT; ++t) {
        // ---- wait for h_{t-1} from the 32 WGs of this rowgroup ----
        if (t > 0) {
            if (tid == 0) {
                const unsigned int* p = &cnt[rg * TT + (t - 1)];
                while (__hip_atomic_load(p, __ATOMIC_ACQUIRE, __HIP_MEMORY_SCOPE_AGENT) < 32u)
                    __builtin_amdgcn_s_sleep(1);
            }
            __syncthreads();
        }

        // ---- stage combined = [x_t | h_{t-1}] rows b0..b0+15 into LDS ----
        {
            const float4* xs = (const float4*)(X + ((size_t)t * BB + b0) * DD);
            #pragma unroll
            for (int i = 0; i < 8; ++i) {
                const int v = tid + i * 256;        // float4 index, 0..2047
                float4 f4 = xs[v];
                const int row = v >> 7;
                const int col = (v & 127) << 2;
                unsigned short* d = &comb[row][col];
                d[0] = f2bfs(f4.x); d[1] = f2bfs(f4.y);
                d[2] = f2bfs(f4.z); d[3] = f2bfs(f4.w);
            }
            const ushort4* hs = (const ushort4*)(hbuf
                + (size_t)((t + 1) & 1) * BB * HH + (size_t)b0 * HH);
            #pragma unroll
            for (int i = 0; i < 8; ++i) {
                const int v = tid + i * 256;        // ushort4 index, 0..2047
                ushort4 u4 = hs[v];
                const int row = v >> 7;
                const int col = (v & 127) << 2;
                unsigned short* d = &comb[row][DD + col];
                d[0] = u4.x; d[1] = u4.y; d[2] = u4.z; d[3] = u4.w;
            }
        }
        __syncthreads();

        // ---- MFMA: 4 "gates" (i,u,o,f-head) over this wave's K-chunk ----
        f32x4 a0 = {0.f, 0.f, 0.f, 0.f}, a1 = a0, a2 = a0, a3 = a0;
        #pragma unroll
        for (int kk = 0; kk < 8; ++kk) {
            const int k = wv * 256 + kk * 32 + qd * 8;
            bf16x8 av = *(const bf16x8*)&comb[nn][k];
            a0 = __builtin_amdgcn_mfma_f32_16x16x32_bf16(av, wfi[kk], a0, 0, 0, 0);
            a1 = __builtin_amdgcn_mfma_f32_16x16x32_bf16(av, wfu[kk], a1, 0, 0, 0);
            a2 = __builtin_amdgcn_mfma_f32_16x16x32_bf16(av, wfo[kk], a2, 0, 0, 0);
            a3 = __builtin_amdgcn_mfma_f32_16x16x32_bf16(av, wff[kk], a3, 0, 0, 0);
        }
        #pragma unroll
        for (int r = 0; r < 4; ++r) {
            pc[0][wv][qd * 4 + r][nn] = a0[r];
            pc[1][wv][qd * 4 + r][nn] = a1[r];
            pc[2][wv][qd * 4 + r][nn] = a2[r];
            pc[3][wv][qd * 4 + r][nn] = a3[r];
        }
        __syncthreads();

        // ---- f-head MLP + softmax (16 threads, one per row) ----
        if (tid < 16) {
            float l0 = bfr0, l1 = bfr1;
            #pragma unroll
            for (int w2 = 0; w2 < 4; ++w2) { l0 += pc[3][w2][tid][0]; l1 += pc[3][w2][tid][1]; }
            float hd[4];
            #pragma unroll
            for (int j = 0; j < 4; ++j)
                hd[j] = tanhf(ws1r[j * 2] * l0 + ws1r[j * 2 + 1] * l1 + bs1r[j]);
            float s0 = bs2r0, s1 = bs2r1;
            #pragma unroll
            for (int j = 0; j < 4; ++j) { s0 += ws2r[j] * hd[j]; s1 += ws2r[4 + j] * hd[j]; }
            fld[tid] = 1.f / (1.f + expf(s1 - s0));
        }
        __syncthreads();

        // ---- gate nonlinearities, c/h update, writes ----
        {
            float ip = bir, up = bur, op = bor;
            #pragma unroll
            for (int w2 = 0; w2 < 4; ++w2) {
                ip += pc[0][w2][fm][fn];
                up += pc[1][w2][fm][fn];
                op += pc[2][w2][fm][fn];
            }
            const float iv = 1.f / (1.f + expf(-ip));
            const float gv = tanhf(up);
            const float ov = 1.f / (1.f + expf(-op));
            cval = fld[fm] * cval + iv * gv;
            const float hv = ov * tanhf(cval);
            const int b = b0 + fm;
            out[((size_t)t * BB + b) * HH + gcol] = hv;
            hbuf[(size_t)(t & 1) * BB * HH + (size_t)b * HH + gcol] = f2bfs(hv);
            if (t == TT - 1) {
                out[(size_t)TT * BB * HH + (size_t)b * HH + gcol] = hv;
                out[(size_t)TT * BB * HH + (size_t)BB * HH + (size_t)b * HH + gcol] = cval;
            }
        }
        __syncthreads();   // all stores issued+drained before arrive

        if (tid == 0)
            __hip_atomic_fetch_add(&cnt[rg * TT + t], 1u,
                                   __ATOMIC_RELEASE, __HIP_MEMORY_SCOPE_AGENT);
    }
}

extern "C" void kernel_launch(void* const* d_in, const int* in_sizes, int n_in,
                              void* d_out, int out_size, void* d_ws, size_t ws_size,
                              hipStream_t stream) {
    const float* X   = (const float*)d_in[0];
    const float* Wf  = (const float*)d_in[1];
    const float* bfb = (const float*)d_in[2];
    const float* Wi  = (const float*)d_in[3];
    const float* bi  = (const float*)d_in[4];
    const float* Wu  = (const float*)d_in[5];
    const float* bu  = (const float*)d_in[6];
    const float* Wo  = (const float*)d_in[7];
    const float* bo  = (const float*)d_in[8];
    const float* Ws1 = (const float*)d_in[9];
    const float* bs1 = (const float*)d_in[10];
    const float* Ws2 = (const float*)d_in[11];
    const float* bs2 = (const float*)d_in[12];
    float* out = (float*)d_out;

    unsigned int*   cnt  = (unsigned int*)d_ws;                       // 8*512*4 = 16 KB
    unsigned short* hbuf = (unsigned short*)((char*)d_ws + 16384);    // 2*128*512*2 = 256 KB

    hipMemsetAsync(d_ws, 0, 16384 + 2 * BB * HH * sizeof(unsigned short), stream);
    qlstm_kernel<<<dim3(256), dim3(256), 0, stream>>>(
        X, Wf, bfb, Wi, bi, Wu, bu, Wo, bo, Ws1, bs1, Ws2, bs2, out, cnt, hbuf);
}

// Round 2
// 5182.561 us; speedup vs baseline: 1.2400x; 1.2400x over previous
//
#include <hip/hip_runtime.h>
#include <cstdint>

#define TT 512
#define BB 128
#define DD 512
#define HH 512
#define KTOT 1024
#define LDK 1032   // padded K stride in LDS (bf16 elements)

typedef short bf16x8 __attribute__((ext_vector_type(8)));
typedef float f32x4 __attribute__((ext_vector_type(4)));

__device__ inline unsigned short f2bfs(float f) {
    unsigned int u = __builtin_bit_cast(unsigned int, f);
    u = (u + 0x7FFFu + ((u >> 16) & 1u)) >> 16;
    return (unsigned short)u;
}

__device__ inline bf16x8 load8w(const float* p) {
    const float4* p4 = (const float4*)p;
    float4 a = p4[0], b = p4[1];
    bf16x8 r;
    r[0] = (short)f2bfs(a.x); r[1] = (short)f2bfs(a.y);
    r[2] = (short)f2bfs(a.z); r[3] = (short)f2bfs(a.w);
    r[4] = (short)f2bfs(b.x); r[5] = (short)f2bfs(b.y);
    r[6] = (short)f2bfs(b.z); r[7] = (short)f2bfs(b.w);
    return r;
}

__global__ __launch_bounds__(256, 1) void qlstm_kernel(
    const float* __restrict__ X,
    const float* __restrict__ Wf, const float* __restrict__ bfb,
    const float* __restrict__ Wi, const float* __restrict__ bi,
    const float* __restrict__ Wu, const float* __restrict__ bu,
    const float* __restrict__ Wo, const float* __restrict__ bo,
    const float* __restrict__ Ws1, const float* __restrict__ bs1,
    const float* __restrict__ Ws2, const float* __restrict__ bs2,
    float* __restrict__ out,
    unsigned int* __restrict__ cnt,      // [8][TT] step barrier counters
    unsigned short* __restrict__ hbuf)   // [2][BB][HH] bf16 ping-pong
{
    const int tid  = threadIdx.x;
    const int bid  = blockIdx.x;
    // XCD-local pipelines: default dispatch maps block i -> XCD i%8, so
    // rg = bid&7 puts all 32 WGs of a rowgroup on ONE XCD (local L2 for h/cnt).
    const int rg   = bid & 7;
    const int cg   = bid >> 3;
    const int b0   = rg * 16;
    const int lane = tid & 63;
    const int wv   = tid >> 6;    // wave -> gate {0:i, 1:u, 2:o, 3:f-head}
    const int qd   = lane >> 4;
    const int nn   = lane & 15;

    __shared__ unsigned short comb[16][LDK];   // staged [x|h] rows, bf16
    __shared__ float pc[4][16][16];            // [gate][m][n]

    // ---- one-time: this wave's gate weights, full K, as B-fragments ----
    bf16x8 wfr[32];
    {
        bf16x8 z8;
        #pragma unroll
        for (int j = 0; j < 8; ++j) z8[j] = 0;
        const float* Wg = (wv == 0) ? Wi : (wv == 1) ? Wu : (wv == 2) ? Wo : Wf;
        const size_t row = (wv == 3) ? (size_t)nn : (size_t)(cg * 16 + nn);
        const bool valid = (wv < 3) || (nn < 2);
        #pragma unroll
        for (int kk = 0; kk < 32; ++kk)
            wfr[kk] = valid ? load8w(Wg + row * KTOT + kk * 32 + qd * 8) : z8;
    }

    // ---- one-time: small params (all threads; f-head computed redundantly) ----
    const int fm = tid >> 4, fn = tid & 15;
    const int gcol = cg * 16 + fn;
    const float bir = bi[gcol], bur = bu[gcol], bor = bo[gcol];
    const float bfr0 = bfb[0], bfr1 = bfb[1];
    float ws1r[8], bs1r[4], ws2r[8];
    #pragma unroll
    for (int j = 0; j < 8; ++j) ws1r[j] = Ws1[j];
    #pragma unroll
    for (int j = 0; j < 4; ++j) bs1r[j] = bs1[j];
    #pragma unroll
    for (int j = 0; j < 8; ++j) ws2r[j] = Ws2[j];
    const float bs2r0 = bs2[0], bs2r1 = bs2[1];

    // ---- prologue: stage X(0) into comb ----
    {
        const float4* xs = (const float4*)(X + (size_t)b0 * DD);
        #pragma unroll
        for (int i = 0; i < 8; ++i) {
            const int v = tid + i * 256;
            float4 f4 = xs[v];
            const int row = v >> 7, col = (v & 127) << 2;
            unsigned short* d = &comb[row][col];
            d[0] = f2bfs(f4.x); d[1] = f2bfs(f4.y);
            d[2] = f2bfs(f4.z); d[3] = f2bfs(f4.w);
        }
    }

    float cval = 0.f;   // persistent cell state for (fm, fn)

    for (int t = 0; t < TT; ++t) {
        // ---- wait for h_{t-1}: relaxed poll, single acquire fence ----
        if (t > 0) {
            if (tid == 0) {
                const unsigned int* p = &cnt[rg * TT + (t - 1)];
                while (__hip_atomic_load(p, __ATOMIC_RELAXED, __HIP_MEMORY_SCOPE_AGENT) < 32u)
                    __builtin_amdgcn_s_sleep(1);
                __builtin_amdgcn_fence(__ATOMIC_ACQUIRE, "agent");
            }
            __syncthreads();
        }

        // ---- stage h_{t-1} rows into comb[.][DD..] ----
        {
            const ushort4* hs = (const ushort4*)(hbuf
                + (size_t)((t + 1) & 1) * BB * HH + (size_t)b0 * HH);
            #pragma unroll
            for (int i = 0; i < 8; ++i) {
                const int v = tid + i * 256;
                ushort4 u4 = hs[v];
                const int row = v >> 7, col = (v & 127) << 2;
                unsigned short* d = &comb[row][DD + col];
                d[0] = u4.x; d[1] = u4.y; d[2] = u4.z; d[3] = u4.w;
            }
        }
        __syncthreads();

        // ---- prefetch X(t+1) into registers (overlaps MFMA) ----
        float4 xp[8];
        {
            const int tn = (t + 1 < TT) ? t + 1 : t;
            const float4* xs = (const float4*)(X + ((size_t)tn * BB + b0) * DD);
            #pragma unroll
            for (int i = 0; i < 8; ++i) xp[i] = xs[tid + i * 256];
        }

        // ---- wave wv computes gate wv over full K; 2 accumulators ----
        f32x4 ac0 = {0.f, 0.f, 0.f, 0.f}, ac1 = ac0;
        #pragma unroll
        for (int kk = 0; kk < 32; kk += 2) {
            bf16x8 av0 = *(const bf16x8*)&comb[nn][kk * 32 + qd * 8];
            bf16x8 av1 = *(const bf16x8*)&comb[nn][(kk + 1) * 32 + qd * 8];
            ac0 = __builtin_amdgcn_mfma_f32_16x16x32_bf16(av0, wfr[kk], ac0, 0, 0, 0);
            ac1 = __builtin_amdgcn_mfma_f32_16x16x32_bf16(av1, wfr[kk + 1], ac1, 0, 0, 0);
        }
        #pragma unroll
        for (int r = 0; r < 4; ++r)
            pc[wv][qd * 4 + r][nn] = ac0[r] + ac1[r];
        __syncthreads();

        // ---- write prefetched X(t+1) into comb (free after acc-sync) ----
        #pragma unroll
        for (int i = 0; i < 8; ++i) {
            const int v = tid + i * 256;
            const int row = v >> 7, col = (v & 127) << 2;
            unsigned short* d = &comb[row][col];
            d[0] = f2bfs(xp[i].x); d[1] = f2bfs(xp[i].y);
            d[2] = f2bfs(xp[i].z); d[3] = f2bfs(xp[i].w);
        }

        // ---- f-head MLP+softmax (redundant per-thread) + gate update ----
        {
            const float l0 = bfr0 + pc[3][fm][0];
            const float l1 = bfr1 + pc[3][fm][1];
            const float hd0 = tanhf(ws1r[0] * l0 + ws1r[1] * l1 + bs1r[0]);
            const float hd1 = tanhf(ws1r[2] * l0 + ws1r[3] * l1 + bs1r[1]);
            const float hd2 = tanhf(ws1r[4] * l0 + ws1r[5] * l1 + bs1r[2]);
            const float hd3 = tanhf(ws1r[6] * l0 + ws1r[7] * l1 + bs1r[3]);
            const float s0 = bs2r0 + ws2r[0]*hd0 + ws2r[1]*hd1 + ws2r[2]*hd2 + ws2r[3]*hd3;
            const float s1 = bs2r1 + ws2r[4]*hd0 + ws2r[5]*hd1 + ws2r[6]*hd2 + ws2r[7]*hd3;
            const float fval = 1.f / (1.f + expf(s1 - s0));

            const float ip = bir + pc[0][fm][fn];
            const float up = bur + pc[1][fm][fn];
            const float op = bor + pc[2][fm][fn];
            const float iv = 1.f / (1.f + expf(-ip));
            const float gv = tanhf(up);
            const float ov = 1.f / (1.f + expf(-op));
            cval = fval * cval + iv * gv;
            const float hv = ov * tanhf(cval);
            const int b = b0 + fm;
            hbuf[(size_t)(t & 1) * BB * HH + (size_t)b * HH + gcol] = f2bfs(hv);
            __syncthreads();   // each wave drains its own vmem before barrier

            if (tid == 0) {
                __builtin_amdgcn_fence(__ATOMIC_RELEASE, "agent");
                __hip_atomic_fetch_add(&cnt[rg * TT + t], 1u,
                                       __ATOMIC_RELAXED, __HIP_MEMORY_SCOPE_AGENT);
            }

            // out stores AFTER the release: off the barrier critical path
            out[((size_t)t * BB + b) * HH + gcol] = hv;
            if (t == TT - 1) {
                out[(size_t)TT * BB * HH + (size_t)b * HH + gcol] = hv;
                out[(size_t)TT * BB * HH + (size_t)BB * HH + (size_t)b * HH + gcol] = cval;
            }
        }
    }
}

extern "C" void kernel_launch(void* const* d_in, const int* in_sizes, int n_in,
                              void* d_out, int out_size, void* d_ws, size_t ws_size,
                              hipStream_t stream) {
    const float* X   = (const float*)d_in[0];
    const float* Wf  = (const float*)d_in[1];
    const float* bfb = (const float*)d_in[2];
    const float* Wi  = (const float*)d_in[3];
    const float* bi  = (const float*)d_in[4];
    const float* Wu  = (const float*)d_in[5];
    const float* bu  = (const float*)d_in[6];
    const float* Wo  = (const float*)d_in[7];
    const float* bo  = (const float*)d_in[8];
    const float* Ws1 = (const float*)d_in[9];
    const float* bs1 = (const float*)d_in[10];
    const float* Ws2 = (const float*)d_in[11];
    const float* bs2 = (const float*)d_in[12];
    float* out = (float*)d_out;

    unsigned int*   cnt  = (unsigned int*)d_ws;                       // 8*512*4 = 16 KB
    unsigned short* hbuf = (unsigned short*)((char*)d_ws + 16384);    // 2*128*512*2 = 256 KB

    hipMemsetAsync(d_ws, 0, 16384 + 2 * BB * HH * sizeof(unsigned short), stream);
    qlstm_kernel<<<dim3(256), dim3(256), 0, stream>>>(
        X, Wf, bfb, Wi, bi, Wu, bu, Wo, bo, Ws1, bs1, Ws2, bs2, out, cnt, hbuf);
}